// Round 22
// baseline (715.161 us; speedup 1.0000x reference)
//
#include <hip/hip_runtime.h>

#define T_STEPS 32
#define BATCH   16
#define NBPB    32                   // blocks per batch
#define NBLK    (BATCH * NBPB)       // 512 blocks
#define NTHR    512                  // 8 waves/block
#define LSL     128                  // l-slots per block (4096/32)
#define MSTR    65                   // LDS stride: bank (l+w)%32 -> 2-way (free)
#define NIN     192
#define CO      332

// comm workspace (floats), zeroed by hipMemsetAsync each launch.
// r16-r18: EVERY 512-block hipLaunchCooperativeKernel produced memset-zero
// output. Decisive: dout[t=0] depends only on inp/Wc block-locally, so ANY
// executing kernel writes nonzero there -> the kernel never ran; cooperative
// launch of >256 blocks fails on this runtime (error unchecked). r20: plain
// hipLaunchKernelGGL. The atomic-spin barrier needs only co-residency:
// 512thr/38KB-LDS/64-VGPR -> 4 blocks/CU = 1024 slots >= 512 blocks (2x).
#define OFF_CTR   0                                        // [16][32] uints (barrier ctrs)
#define OFF_SSUM  512                                      // [b][t][4]  S_R,S_W,P_R,P_W
#define OFF_RSUM  (OFF_SSUM + BATCH * T_STEPS * 4)         // [b][t][64] unnormalized read partials
#define OFF_HE    (OFF_RSUM + BATCH * T_STEPS * 64)        // [b][2][g][4] er halos (slot t&1)
#define OFF_HP    (OFF_HE + BATCH * 2 * NBPB * 4)          // [b][2][g][4] wp halos (slot t&1 = state t)
#define COMM_FLOATS (OFF_HP + BATCH * 2 * NBPB * 4)

__device__ __forceinline__ float waveSum(float v) {
#pragma unroll
  for (int off = 32; off > 0; off >>= 1) v += __shfl_xor(v, off, 64);
  return v;
}
__device__ __forceinline__ float sigmoidf(float x) { return 1.f / (1.f + __expf(-x)); }
__device__ __forceinline__ float softplusf(float x) { return x > 15.f ? x : log1pf(__expf(x)); }
__device__ __forceinline__ float aload(const float* p) {
  return __hip_atomic_load(p, __ATOMIC_RELAXED, __HIP_MEMORY_SCOPE_AGENT);
}
__device__ __forceinline__ void astore(float* p, float v) {
  __hip_atomic_store(p, v, __ATOMIC_RELAXED, __HIP_MEMORY_SCOPE_AGENT);
}

// 32-block per-batch barrier, r0 form. __syncthreads drains each thread's
// outstanding vmem/atomics before thread 0 bumps the counter.
__device__ __forceinline__ void gbar(unsigned* c, unsigned expected) {
  __syncthreads();
  if (threadIdx.x == 0) {
    atomicAdd(c, 1u);
    while (__hip_atomic_load(c, __ATOMIC_RELAXED, __HIP_MEMORY_SCOPE_AGENT) < expected)
      __builtin_amdgcn_s_sleep(1);
  }
  __syncthreads();
}

// Halo-slot safety (2 slots over t-parity): HE slot t&1 read by neighbors in
// phase2(t) (before their B(t) bump), next written phase1(t+2) -- after the
// writer passed B(t+1) -> after ALL blocks finished phase2(t+1). HP slot t&1
// (state t): read phase2(t), rewritten phase3(t+1) -- same ordering. No WAR.
__global__ void __launch_bounds__(NTHR, 1) ntm_kernel(
    const float* __restrict__ inp, const float* __restrict__ Wc,
    const float* __restrict__ bcv, float* __restrict__ dout,
    float* __restrict__ comm)
{
  // XCD co-location: blockIdx = g*16 + b -> blockIdx%8 == b%8, so all 32
  // blocks of a batch land on one XCD (round-robin dispatch) -> local-L2 atomics.
  const int b   = blockIdx.x & 15;
  const int g   = blockIdx.x >> 4;            // 0..31
  const int tid = threadIdx.x;
  const int wv  = tid >> 6;                   // 0..7
  const int lane = tid & 63;

  __shared__ float mem[LSL * MSTR];               // 33.3 KB, block-private
  __shared__ float wpR[LSL], wpW[LSL];            // normalized prev weights
  __shared__ float wbR[LSL], wbW[LSL];            // sharpened, unnormalized
  __shared__ float erR[LSL], erW[LSL];            // softmax numerators
  __shared__ float xin[NIN], kr[64], kw[64], psc[12], elds[64], alds[64];
  __shared__ float outb[2][64], scrA[8], scrB[8], red[8], rpart[64];
  __shared__ float edge[8], coef[12];

  unsigned* ctr = (unsigned*)comm + b * 32;

  // ---------------- prologue ----------------
  for (int i = tid; i < LSL * MSTR; i += NTHR) mem[i] = 0.f;
  if (tid < LSL) { wpR[tid] = 0.f; wpW[tid] = 0.f; }
  if (g == 0 && tid == 0) { wpR[0] = 1.f; wpW[0] = 1.f; }  // w0 one-hot at l=0
  if (tid < 64) { outb[0][tid] = 0.f; outb[1][tid] = 0.f; }
  {
    float* hp0 = comm + OFF_HP + ((size_t)(b * 2 + 0) * NBPB + g) * 4;   // state t=0, slot 0
    if (tid == 0)       { float v = (g == 0) ? 1.f : 0.f; astore(hp0 + 0, v); astore(hp0 + 2, v); }
    if (tid == LSL - 1) { astore(hp0 + 1, 0.f); astore(hp0 + 3, 0.f); }
  }
  unsigned expct = NBPB;
  gbar(ctr, expct);

  for (int t = 0; t < T_STEPS; ++t) {
    float* sS  = comm + OFF_SSUM + (size_t)(b * T_STEPS + t) * 4;
    float* rS  = comm + OFF_RSUM + (size_t)(b * T_STEPS + t) * 64;
    float* hE  = comm + OFF_HE + ((size_t)(b * 2 + (t & 1)) * NBPB + g) * 4;
    float* hPn = comm + OFF_HP + ((size_t)(b * 2 + ((t + 1) & 1)) * NBPB + g) * 4;

    // ---------------- phase 0: stage input + controller GEMM ----------------
    if (tid < 64)       xin[tid] = inp[((size_t)t * BATCH + b) * 64 + tid];
    else if (tid < 128) xin[tid] = outb[(t + 1) & 1][tid - 64];
    else if (tid < 192) {
      if (t == 0) xin[tid] = 0.f;
      else {
        const float* sP = comm + OFF_SSUM + (size_t)(b * T_STEPS + t - 1) * 4;
        const float* rP = comm + OFF_RSUM + (size_t)(b * T_STEPS + t - 1) * 64;
        xin[tid] = aload(rP + (tid - 128)) / aload(sP + 2);   // r = r~ / P_R
      }
    }
    __syncthreads();

    // 1 thread per output col (332 <= 512); dual accumulators keep the FMA
    // dependency chain at 96 (r15-equal).
    if (tid < CO) {
      const float* wcp = Wc + tid;
      float a0 = bcv[tid], a1 = 0.f;
#pragma unroll 8
      for (int i = 0; i < 96; ++i) {
        a0 = fmaf(xin[i],      wcp[(size_t)i * CO],        a0);
        a1 = fmaf(xin[96 + i], wcp[(size_t)(96 + i) * CO], a1);
      }
      const float acc = a0 + a1;
      if (tid < 64) {
        outb[t & 1][tid] = acc;
        if (g == 0) dout[((size_t)t * BATCH + b) * 64 + tid] = acc;
      }
      else if (tid < 128) kr[tid - 64] = acc;
      else if (tid < 134) psc[tid - 128] = acc;        // beta_r,g_r,ga_r,s_r0..2
      else if (tid < 198) kw[tid - 134] = acc;
      else if (tid < 204) psc[6 + (tid - 198)] = acc;  // beta_w,g_w,ga_w,s_w0..2
      else if (tid < 268) elds[tid - 204] = sigmoidf(acc);
      else                alds[tid - 268] = acc;
    }
    __syncthreads();
    if (wv == 0)      { float v = kr[lane]; float s = waveSum(v * v); if (!lane) red[4] = 1.f / sqrtf(s + 1e-14f); }
    else if (wv == 1) { float v = kw[lane]; float s = waveSum(v * v); if (!lane) red[5] = 1.f / sqrtf(s + 1e-14f); }
    else if (wv == 2 && !lane) { red[6] = softplusf(psc[0]); red[7] = softplusf(psc[6]); }
    __syncthreads();

    // ---------------- phase 1: content addressing (4 threads per l) ----------------
    {
      const float invnkR = red[4], invnkW = red[5];
      const float betaR = red[6], betaW = red[7];
      const int l = tid >> 2, h = tid & 3;              // l: 0..127
      const int base = l * MSTR + 16 * h;
      const float* krh = kr + 16 * h;
      const float* kwh = kw + 16 * h;
      float ss = 0.f, dr = 0.f, dw = 0.f;
#pragma unroll 8
      for (int i = 0; i < 16; ++i) {
        float v = mem[base + i];
        ss = fmaf(v, v, ss); dr = fmaf(v, krh[i], dr); dw = fmaf(v, kwh[i], dw);
      }
      ss += __shfl_xor(ss, 1, 64); ss += __shfl_xor(ss, 2, 64);
      dr += __shfl_xor(dr, 1, 64); dr += __shfl_xor(dr, 2, 64);
      dw += __shfl_xor(dw, 1, 64); dw += __shfl_xor(dw, 2, 64);
      float rinv = rsqrtf(ss + 1e-14f);
      float eRv = __expf(betaR * (dr * rinv * invnkR - 1.f));   // stable: K<=1
      float eWv = __expf(betaW * (dw * rinv * invnkW - 1.f));
      if (h == 0) {
        erR[l] = eRv; erW[l] = eWv;
        if (l == 0)       { astore(hE + 0, eRv); astore(hE + 2, eWv); }
        if (l == LSL - 1) { astore(hE + 1, eRv); astore(hE + 3, eWv); }
      }
      float sRl = h ? 0.f : eRv, sWl = h ? 0.f : eWv;
      sRl = waveSum(sRl); sWl = waveSum(sWl);
      if (!lane) { scrA[wv] = sRl; scrB[wv] = sWl; }
      __syncthreads();
      if (tid == 0) {
        float a = 0.f, bb = 0.f;
        for (int j = 0; j < 8; ++j) { a += scrA[j]; bb += scrB[j]; }
        atomicAdd(sS + 0, a); atomicAdd(sS + 1, bb);
      }
    }
    expct += NBPB; gbar(ctr, expct);   // barrier A

    // ---------------- phase 2: sharpen + unnormalized read partials ----------------
    {
      const int gm = (g + NBPB - 1) & (NBPB - 1), gp = (g + 1) & (NBPB - 1);
      if (tid == 0) {
        float invSR = 1.f / aload(sS + 0), invSW = 1.f / aload(sS + 1);
        float gR = sigmoidf(psc[1]); coef[0] = gR * invSR; coef[1] = 1.f - gR;
        coef[2] = softplusf(psc[2]) + 1.f;
        float x0 = psc[3], x1 = psc[4], x2 = psc[5];
        float mx = fmaxf(x0, fmaxf(x1, x2));
        float e0 = __expf(x0 - mx), e1 = __expf(x1 - mx), e2 = __expf(x2 - mx);
        float es = 1.f / (e0 + e1 + e2);
        coef[3] = e0 * es; coef[4] = e1 * es; coef[5] = e2 * es;
        float gW = sigmoidf(psc[7]); coef[6] = gW * invSW; coef[7] = 1.f - gW;
        coef[8] = softplusf(psc[8]) + 1.f;
        float y0 = psc[9], y1 = psc[10], y2 = psc[11];
        float my = fmaxf(y0, fmaxf(y1, y2));
        float f0 = __expf(y0 - my), f1 = __expf(y1 - my), f2 = __expf(y2 - my);
        float fs = 1.f / (f0 + f1 + f2);
        coef[9] = f0 * fs; coef[10] = f1 * fs; coef[11] = f2 * fs;
      }
      if (tid == 1) {
        const float* hEm = comm + OFF_HE + ((size_t)(b * 2 + (t & 1)) * NBPB + gm) * 4;
        const float* hPm = comm + OFF_HP + ((size_t)(b * 2 + (t & 1)) * NBPB + gm) * 4;
        edge[0] = aload(hEm + 1); edge[1] = aload(hEm + 3);
        edge[2] = aload(hPm + 1); edge[3] = aload(hPm + 3);
      }
      if (tid == 2) {
        const float* hEp = comm + OFF_HE + ((size_t)(b * 2 + (t & 1)) * NBPB + gp) * 4;
        const float* hPp = comm + OFF_HP + ((size_t)(b * 2 + (t & 1)) * NBPB + gp) * 4;
        edge[4] = aload(hEp + 0); edge[5] = aload(hEp + 2);
        edge[6] = aload(hPp + 0); edge[7] = aload(hPp + 2);
      }
      __syncthreads();

      float pRl = 0.f, pWl = 0.f;
      if (tid < LSL) {
        const float aR = coef[0], bR = coef[1], gaR = coef[2];
        const float sr0 = coef[3], sr1 = coef[4], sr2 = coef[5];
        const float aW = coef[6], bW = coef[7], gaW = coef[8];
        const float sw0 = coef[9], sw1 = coef[10], sw2 = coef[11];

        float erm = tid ? erR[tid - 1] : edge[0];
        float ewm = tid ? erW[tid - 1] : edge[1];
        float prm = tid ? wpR[tid - 1] : edge[2];
        float pwm = tid ? wpW[tid - 1] : edge[3];
        float erp = (tid < LSL - 1) ? erR[tid + 1] : edge[4];
        float ewp = (tid < LSL - 1) ? erW[tid + 1] : edge[5];
        float prp = (tid < LSL - 1) ? wpR[tid + 1] : edge[6];
        float pwp = (tid < LSL - 1) ? wpW[tid + 1] : edge[7];

        float wgm = aR * erm + bR * prm;
        float wg0 = aR * erR[tid] + bR * wpR[tid];
        float wgp = aR * erp + bR * prp;
        float wR = __powf(sr0 * wgm + sr1 * wg0 + sr2 * wgp, gaR);
        float vgm = aW * ewm + bW * pwm;
        float vg0 = aW * erW[tid] + bW * wpW[tid];
        float vgp = aW * ewp + bW * pwp;
        float wW = __powf(sw0 * vgm + sw1 * vg0 + sw2 * vgp, gaW);
        wbR[tid] = wR; wbW[tid] = wW;
        pRl = wR; pWl = wW;
      }
      pRl = waveSum(pRl); pWl = waveSum(pWl);
      if (!lane && wv < 2) { scrA[wv] = pRl; scrB[wv] = pWl; }
      __syncthreads();
      if (tid == 0) {
        float a = 0.f, bb = 0.f;
        for (int j = 0; j < 2; ++j) { a += scrA[j]; bb += scrB[j]; }
        atomicAdd(sS + 2, a); atomicAdd(sS + 3, bb);
      }
      // unnormalized read partials r~ = sum_l wbR[l] * mem[l][w] (OLD memory)
      float wbv[2];
#pragma unroll
      for (int k = 0; k < 2; ++k) wbv[k] = wbR[lane + 64 * k];
#pragma unroll
      for (int r2 = 0; r2 < 8; ++r2) {
        const int w = wv * 8 + r2;
        float racc = 0.f;
#pragma unroll
        for (int k = 0; k < 2; ++k)
          racc = fmaf(mem[(lane + 64 * k) * MSTR + w], wbv[k], racc);
        racc = waveSum(racc);
        if (!lane) rpart[w] = racc;
      }
      __syncthreads();
      if (tid < 64) atomicAdd(rS + tid, rpart[tid]);
    }
    expct += NBPB; gbar(ctr, expct);   // barrier B (last of the step)

    // ---------------- phase 3: normalize weights + memory update (local only) ----------------
    {
      if (tid == 0) { red[2] = 1.f / aload(sS + 2); red[3] = 1.f / aload(sS + 3); }
      __syncthreads();
      if (tid < LSL) {
        float nR = wbR[tid] * red[2];
        float nW = wbW[tid] * red[3];
        wpR[tid] = nR; wpW[tid] = nW;       // w_prev for t+1
        if (tid == 0)       { astore(hPn + 0, nR); astore(hPn + 2, nW); }
        if (tid == LSL - 1) { astore(hPn + 1, nR); astore(hPn + 3, nW); }
      }
      __syncthreads();
      float wwv[2];
#pragma unroll
      for (int k = 0; k < 2; ++k) wwv[k] = wpW[lane + 64 * k];
#pragma unroll
      for (int r2 = 0; r2 < 8; ++r2) {
        const int w = wv * 8 + r2;
        const float e_w = elds[w], a_w = alds[w];
#pragma unroll
        for (int k = 0; k < 2; ++k) {
          const int idx = (lane + 64 * k) * MSTR + w;
          float v = mem[idx];
          float nv = fmaf(v, -(wwv[k] * e_w), v);     // v*(1 - ww*e)
          mem[idx] = fmaf(wwv[k], a_w, nv);           // + ww*a
        }
      }
      // no barrier: next step's phase-0 __syncthreads orders LDS; halo stores
      // drain at barrier A of t+1 before any neighbor reads them.
    }
  }
}

extern "C" void kernel_launch(void* const* d_in, const int* in_sizes, int n_in,
                              void* d_out, int out_size, void* d_ws, size_t ws_size,
                              hipStream_t stream) {
  const float* inp = (const float*)d_in[0];
  const float* Wc  = (const float*)d_in[1];
  const float* bcv = (const float*)d_in[2];
  float* dout = (float*)d_out;
  float* comm = (float*)d_ws;

  hipMemsetAsync(comm, 0, (size_t)COMM_FLOATS * sizeof(float), stream);

  // Plain launch (NOT cooperative): the runtime rejected every 512-block
  // cooperative grid (r16-r18, output untouched). Our barrier only needs
  // co-residency; capacity is 4 blocks/CU (threads, LDS, VGPR all allow it)
  // = 1024 slots for 512 blocks, so all blocks are resident immediately.
  hipLaunchKernelGGL(ntm_kernel, dim3(NBLK), dim3(NTHR), 0, stream,
                     inp, Wc, bcv, dout, comm);
}

// Round 23
// 653.081 us; speedup vs baseline: 1.0951x; 1.0951x over previous
//
#include <hip/hip_runtime.h>

#define T_STEPS 32
#define BATCH   16
#define NBPB    16                   // blocks per batch -- measured optimum (8:635, 16:605, 32:690)
#define NBLK    (BATCH * NBPB)       // 256
#define NTHR    1024
#define LSL     256                  // l-slots per block (4096/16)
#define MSTR    65                   // LDS stride: bank (l+w)%32 -> 2-way (free)
#define NIN     192
#define CO      332

// comm workspace (floats), zeroed by hipMemsetAsync each launch
#define OFF_CTR   0                                        // [16][32] uints (barrier ctrs)
#define OFF_SSUM  512                                      // [b][t][4]  S_R,S_W,P_R,P_W
#define OFF_RSUM  (OFF_SSUM + BATCH * T_STEPS * 4)         // [b][t][64] unnormalized read partials
#define OFF_HE    (OFF_RSUM + BATCH * T_STEPS * 64)        // [b][t][g][4] er halos
#define OFF_HP    (OFF_HE + BATCH * T_STEPS * NBPB * 4)    // [b][t=0..32][g][4] normalized wp halos
#define COMM_FLOATS (OFF_HP + BATCH * (T_STEPS + 1) * NBPB * 4)

__device__ __forceinline__ float waveSum(float v) {
#pragma unroll
  for (int off = 32; off > 0; off >>= 1) v += __shfl_xor(v, off, 64);
  return v;
}
__device__ __forceinline__ float sigmoidf(float x) { return 1.f / (1.f + __expf(-x)); }
__device__ __forceinline__ float softplusf(float x) { return x > 15.f ? x : log1pf(__expf(x)); }
__device__ __forceinline__ float aload(const float* p) {
  return __hip_atomic_load(p, __ATOMIC_RELAXED, __HIP_MEMORY_SCOPE_AGENT);
}
__device__ __forceinline__ void astore(float* p, float v) {
  __hip_atomic_store(p, v, __ATOMIC_RELAXED, __HIP_MEMORY_SCOPE_AGENT);
}

// 16-block per-batch barrier. __syncthreads drains each thread's outstanding
// vmem/atomics before thread 0 bumps the counter.
__device__ __forceinline__ void gbar(unsigned* c, unsigned expected) {
  __syncthreads();
  if (threadIdx.x == 0) {
    atomicAdd(c, 1u);
    while (__hip_atomic_load(c, __ATOMIC_RELAXED, __HIP_MEMORY_SCOPE_AGENT) < expected)
      __builtin_amdgcn_s_sleep(1);
  }
  __syncthreads();
}

// Session findings baked in:
//  - r1..r12: every intra-step structural edit (GEMM restructure, redundant-
//    compute sync removal, vectorized/swizzled LDS, reg-resident weights)
//    regresses via scratch+VALU at the 64-VGPR allocation. Keep r0 phase form.
//  - r13/r15/r22: NBPB sweep 8/16/32 -> 635/605/690 us. 16 is the optimum:
//    all 256 CUs active, halved LDS scans, without doubled GEMM redundancy
//    and wider barriers that NBPB=32 pays.
//  - Residual: VALUBusy 16.6% @ 47% occupancy, HBM 0.2% -> barrier-RTT +
//    serial-chain latency floor of the 32-step recurrence, not a HW roofline.
__global__ void __launch_bounds__(NTHR, 1) ntm_kernel(
    const float* __restrict__ inp, const float* __restrict__ Wc,
    const float* __restrict__ bcv, float* __restrict__ dout,
    float* __restrict__ comm)
{
  // XCD co-location: blockIdx = g*16 + b -> blockIdx%8 == b%8, so all 16
  // blocks of a batch land on one XCD (round-robin dispatch) -> local-L2 atomics.
  const int b   = blockIdx.x & 15;
  const int g   = blockIdx.x >> 4;            // 0..15
  const int tid = threadIdx.x;
  const int wv  = tid >> 6;
  const int lane = tid & 63;

  __shared__ float mem[LSL * MSTR];               // 66.5 KB, block-private
  __shared__ float wpR[LSL], wpW[LSL];            // normalized prev weights
  __shared__ float wbR[LSL], wbW[LSL];            // sharpened, unnormalized
  __shared__ float erR[LSL], erW[LSL];            // softmax numerators
  __shared__ float xin[NIN], kr[64], kw[64], psc[12], elds[64], alds[64];
  __shared__ float outb[2][64], scrA[16], scrB[16], red[8], rpart[64];
  __shared__ float edge[8], coef[12];

  unsigned* ctr = (unsigned*)comm + b * 32;

  // ---------------- prologue ----------------
  for (int i = tid; i < LSL * MSTR; i += NTHR) mem[i] = 0.f;
  if (tid < LSL) { wpR[tid] = 0.f; wpW[tid] = 0.f; }
  if (g == 0 && tid == 0) { wpR[0] = 1.f; wpW[0] = 1.f; }  // w0 one-hot at l=0
  if (tid < 64) { outb[0][tid] = 0.f; outb[1][tid] = 0.f; }
  {
    float* hp0 = comm + OFF_HP + ((size_t)(b * (T_STEPS + 1) + 0) * NBPB + g) * 4;
    if (tid == 0)       { float v = (g == 0) ? 1.f : 0.f; astore(hp0 + 0, v); astore(hp0 + 2, v); }
    if (tid == LSL - 1) { astore(hp0 + 1, 0.f); astore(hp0 + 3, 0.f); }
  }
  unsigned expct = NBPB;
  gbar(ctr, expct);

  for (int t = 0; t < T_STEPS; ++t) {
    float* sS  = comm + OFF_SSUM + (size_t)(b * T_STEPS + t) * 4;
    float* rS  = comm + OFF_RSUM + (size_t)(b * T_STEPS + t) * 64;
    float* hE  = comm + OFF_HE + ((size_t)(b * T_STEPS + t) * NBPB + g) * 4;
    float* hPn = comm + OFF_HP + ((size_t)(b * (T_STEPS + 1) + t + 1) * NBPB + g) * 4;

    // ---------------- phase 0: stage input + controller GEMM ----------------
    if (tid < 64)       xin[tid] = inp[((size_t)t * BATCH + b) * 64 + tid];
    else if (tid < 128) xin[tid] = outb[(t + 1) & 1][tid - 64];
    else if (tid < 192) {
      if (t == 0) xin[tid] = 0.f;
      else {
        const float* sP = comm + OFF_SSUM + (size_t)(b * T_STEPS + t - 1) * 4;
        const float* rP = comm + OFF_RSUM + (size_t)(b * T_STEPS + t - 1) * 64;
        xin[tid] = aload(rP + (tid - 128)) / aload(sP + 2);   // r = r~ / P_R
      }
    }
    __syncthreads();

    if (tid < 2 * CO) {
      const int col = tid >> 1, h = tid & 1;
      float acc = h ? 0.f : bcv[col];
      const float* wcp = Wc + col + (size_t)(96 * h) * CO;
#pragma unroll 8
      for (int i = 0; i < 96; ++i) acc = fmaf(xin[96 * h + i], wcp[(size_t)i * CO], acc);
      acc += __shfl_xor(acc, 1, 64);
      if (h == 0) {
        if (col < 64) {
          outb[t & 1][col] = acc;
          if (g == 0) dout[((size_t)t * BATCH + b) * 64 + col] = acc;
        }
        else if (col < 128) kr[col - 64] = acc;
        else if (col < 134) psc[col - 128] = acc;        // beta_r,g_r,ga_r,s_r0..2
        else if (col < 198) kw[col - 134] = acc;
        else if (col < 204) psc[6 + (col - 198)] = acc;  // beta_w,g_w,ga_w,s_w0..2
        else if (col < 268) elds[col - 204] = sigmoidf(acc);
        else                alds[col - 268] = acc;
      }
    }
    __syncthreads();
    if (wv == 0)      { float v = kr[lane]; float s = waveSum(v * v); if (!lane) red[4] = 1.f / sqrtf(s + 1e-14f); }
    else if (wv == 1) { float v = kw[lane]; float s = waveSum(v * v); if (!lane) red[5] = 1.f / sqrtf(s + 1e-14f); }
    else if (wv == 2 && !lane) { red[6] = softplusf(psc[0]); red[7] = softplusf(psc[6]); }
    __syncthreads();

    // ---------------- phase 1: content addressing (4 threads per l) ----------------
    {
      const float invnkR = red[4], invnkW = red[5];
      const float betaR = red[6], betaW = red[7];
      const int l = tid >> 2, h = tid & 3;
      const int base = l * MSTR + 16 * h;
      const float* krh = kr + 16 * h;
      const float* kwh = kw + 16 * h;
      float ss = 0.f, dr = 0.f, dw = 0.f;
#pragma unroll 8
      for (int i = 0; i < 16; ++i) {
        float v = mem[base + i];
        ss = fmaf(v, v, ss); dr = fmaf(v, krh[i], dr); dw = fmaf(v, kwh[i], dw);
      }
      ss += __shfl_xor(ss, 1, 64); ss += __shfl_xor(ss, 2, 64);
      dr += __shfl_xor(dr, 1, 64); dr += __shfl_xor(dr, 2, 64);
      dw += __shfl_xor(dw, 1, 64); dw += __shfl_xor(dw, 2, 64);
      float rinv = rsqrtf(ss + 1e-14f);
      float eRv = __expf(betaR * (dr * rinv * invnkR - 1.f));   // stable: K<=1
      float eWv = __expf(betaW * (dw * rinv * invnkW - 1.f));
      if (h == 0) {
        erR[l] = eRv; erW[l] = eWv;
        if (l == 0)       { astore(hE + 0, eRv); astore(hE + 2, eWv); }
        if (l == LSL - 1) { astore(hE + 1, eRv); astore(hE + 3, eWv); }
      }
      float sRl = h ? 0.f : eRv, sWl = h ? 0.f : eWv;
      sRl = waveSum(sRl); sWl = waveSum(sWl);
      if (!lane) { scrA[wv] = sRl; scrB[wv] = sWl; }
      __syncthreads();
      if (tid == 0) {
        float a = 0.f, bb = 0.f;
        for (int j = 0; j < 16; ++j) { a += scrA[j]; bb += scrB[j]; }
        atomicAdd(sS + 0, a); atomicAdd(sS + 1, bb);
      }
    }
    expct += NBPB; gbar(ctr, expct);   // barrier A

    // ---------------- phase 2: sharpen + unnormalized read partials ----------------
    {
      const int gm = (g + NBPB - 1) & (NBPB - 1), gp = (g + 1) & (NBPB - 1);
      if (tid == 0) {
        float invSR = 1.f / aload(sS + 0), invSW = 1.f / aload(sS + 1);
        float gR = sigmoidf(psc[1]); coef[0] = gR * invSR; coef[1] = 1.f - gR;
        coef[2] = softplusf(psc[2]) + 1.f;
        float x0 = psc[3], x1 = psc[4], x2 = psc[5];
        float mx = fmaxf(x0, fmaxf(x1, x2));
        float e0 = __expf(x0 - mx), e1 = __expf(x1 - mx), e2 = __expf(x2 - mx);
        float es = 1.f / (e0 + e1 + e2);
        coef[3] = e0 * es; coef[4] = e1 * es; coef[5] = e2 * es;
        float gW = sigmoidf(psc[7]); coef[6] = gW * invSW; coef[7] = 1.f - gW;
        coef[8] = softplusf(psc[8]) + 1.f;
        float y0 = psc[9], y1 = psc[10], y2 = psc[11];
        float my = fmaxf(y0, fmaxf(y1, y2));
        float f0 = __expf(y0 - my), f1 = __expf(y1 - my), f2 = __expf(y2 - my);
        float fs = 1.f / (f0 + f1 + f2);
        coef[9] = f0 * fs; coef[10] = f1 * fs; coef[11] = f2 * fs;
      }
      if (tid == 1) {
        const float* hEm = comm + OFF_HE + ((size_t)(b * T_STEPS + t) * NBPB + gm) * 4;
        const float* hPm = comm + OFF_HP + ((size_t)(b * (T_STEPS + 1) + t) * NBPB + gm) * 4;
        edge[0] = aload(hEm + 1); edge[1] = aload(hEm + 3);
        edge[2] = aload(hPm + 1); edge[3] = aload(hPm + 3);
      }
      if (tid == 2) {
        const float* hEp = comm + OFF_HE + ((size_t)(b * T_STEPS + t) * NBPB + gp) * 4;
        const float* hPp = comm + OFF_HP + ((size_t)(b * (T_STEPS + 1) + t) * NBPB + gp) * 4;
        edge[4] = aload(hEp + 0); edge[5] = aload(hEp + 2);
        edge[6] = aload(hPp + 0); edge[7] = aload(hPp + 2);
      }
      __syncthreads();

      float pRl = 0.f, pWl = 0.f;
      if (tid < LSL) {
        const float aR = coef[0], bR = coef[1], gaR = coef[2];
        const float sr0 = coef[3], sr1 = coef[4], sr2 = coef[5];
        const float aW = coef[6], bW = coef[7], gaW = coef[8];
        const float sw0 = coef[9], sw1 = coef[10], sw2 = coef[11];

        float erm = tid ? erR[tid - 1] : edge[0];
        float ewm = tid ? erW[tid - 1] : edge[1];
        float prm = tid ? wpR[tid - 1] : edge[2];
        float pwm = tid ? wpW[tid - 1] : edge[3];
        float erp = (tid < LSL - 1) ? erR[tid + 1] : edge[4];
        float ewp = (tid < LSL - 1) ? erW[tid + 1] : edge[5];
        float prp = (tid < LSL - 1) ? wpR[tid + 1] : edge[6];
        float pwp = (tid < LSL - 1) ? wpW[tid + 1] : edge[7];

        float wgm = aR * erm + bR * prm;
        float wg0 = aR * erR[tid] + bR * wpR[tid];
        float wgp = aR * erp + bR * prp;
        float wR = __powf(sr0 * wgm + sr1 * wg0 + sr2 * wgp, gaR);
        float vgm = aW * ewm + bW * pwm;
        float vg0 = aW * erW[tid] + bW * wpW[tid];
        float vgp = aW * ewp + bW * pwp;
        float wW = __powf(sw0 * vgm + sw1 * vg0 + sw2 * vgp, gaW);
        wbR[tid] = wR; wbW[tid] = wW;
        pRl = wR; pWl = wW;
      }
      pRl = waveSum(pRl); pWl = waveSum(pWl);
      if (!lane && wv < 4) { scrA[wv] = pRl; scrB[wv] = pWl; }
      __syncthreads();
      if (tid == 0) {
        float a = 0.f, bb = 0.f;
        for (int j = 0; j < 4; ++j) { a += scrA[j]; bb += scrB[j]; }
        atomicAdd(sS + 2, a); atomicAdd(sS + 3, bb);
      }
      // unnormalized read partials r~ = sum_l wbR[l] * mem[l][w] (OLD memory)
      float wbv[4];
#pragma unroll
      for (int k = 0; k < 4; ++k) wbv[k] = wbR[lane + 64 * k];
#pragma unroll
      for (int r2 = 0; r2 < 4; ++r2) {
        const int w = wv * 4 + r2;
        float racc = 0.f;
#pragma unroll
        for (int k = 0; k < 4; ++k)
          racc = fmaf(mem[(lane + 64 * k) * MSTR + w], wbv[k], racc);
        racc = waveSum(racc);
        if (!lane) rpart[w] = racc;
      }
      __syncthreads();
      if (tid < 64) atomicAdd(rS + tid, rpart[tid]);
    }
    expct += NBPB; gbar(ctr, expct);   // barrier B (last of the step)

    // ---------------- phase 3: normalize weights + memory update (local only) ----------------
    {
      if (tid == 0) { red[2] = 1.f / aload(sS + 2); red[3] = 1.f / aload(sS + 3); }
      __syncthreads();
      if (tid < LSL) {
        float nR = wbR[tid] * red[2];
        float nW = wbW[tid] * red[3];
        wpR[tid] = nR; wpW[tid] = nW;       // w_prev for t+1
        if (tid == 0)       { astore(hPn + 0, nR); astore(hPn + 2, nW); }
        if (tid == LSL - 1) { astore(hPn + 1, nR); astore(hPn + 3, nW); }
      }
      __syncthreads();
      float wwv[4];
#pragma unroll
      for (int k = 0; k < 4; ++k) wwv[k] = wpW[lane + 64 * k];
#pragma unroll
      for (int r2 = 0; r2 < 4; ++r2) {
        const int w = wv * 4 + r2;
        const float e_w = elds[w], a_w = alds[w];
#pragma unroll
        for (int k = 0; k < 4; ++k) {
          const int idx = (lane + 64 * k) * MSTR + w;
          float v = mem[idx];
          float nv = fmaf(v, -(wwv[k] * e_w), v);     // v*(1 - ww*e)
          mem[idx] = fmaf(wwv[k], a_w, nv);           // + ww*a
        }
      }
      // no barrier: next step's phase-0 __syncthreads orders LDS; halo stores
      // drain at barrier A of t+1 before any neighbor reads them.
    }
  }
}

extern "C" void kernel_launch(void* const* d_in, const int* in_sizes, int n_in,
                              void* d_out, int out_size, void* d_ws, size_t ws_size,
                              hipStream_t stream) {
  const float* inp = (const float*)d_in[0];
  const float* Wc  = (const float*)d_in[1];
  const float* bcv = (const float*)d_in[2];
  float* dout = (float*)d_out;
  float* comm = (float*)d_ws;

  hipMemsetAsync(comm, 0, (size_t)COMM_FLOATS * sizeof(float), stream);

  void* args[] = { (void*)&inp, (void*)&Wc, (void*)&bcv, (void*)&dout, (void*)&comm };
  hipLaunchCooperativeKernel((void*)ntm_kernel, dim3(NBLK), dim3(NTHR),
                             args, 0, stream);
}